// Round 5
// baseline (164.812 us; speedup 1.0000x reference)
//
#include <hip/hip_runtime.h>

#define BB   1024
#define TT   512
#define NIN  28
#define NOUT 28
#define NS   4
#define MM   7
#define WW   457          // TT - NIN - NOUT + 1
#define SLEN 519          // MM + 1 + TT - 1
#define EMB  9            // 1 + 1 + MM

#define OUT1_SZ (WW * BB * 144)
#define OUT2_SZ (WW * BB * 28)
#define OUT3_SZ (BB * TT)
#define OUT4_SZ (BB * SLEN)

#define CH   32
#define NCH  (TT / CH)    // 16

typedef float f4 __attribute__((ext_vector_type(4)));

__device__ __forceinline__ f4 ld4u(const float* p) {   // 4B-aligned 16B load
    f4 v;
    __builtin_memcpy(&v, p, sizeof(f4));
    return v;
}

// ---------------------------------------------------------------------------
// Kernel 1: ES scan. 16 blocks x 64 threads; global->reg prefetch dbuf;
// LDS staging for coalesced global I/O. ~5-8 us.
// ---------------------------------------------------------------------------
__global__ __launch_bounds__(64) void es_scan(const float* __restrict__ Y,
        const int* __restrict__ idxs, const float* __restrict__ EW,
        float* __restrict__ levels, float* __restrict__ seas) {
    __shared__ float yl[64][CH + 1];
    __shared__ float se[64][CH + 1];
    const int tid = threadIdx.x;
    const int b0  = blockIdx.x << 6;
    const int b   = b0 + tid;

    const float* e = EW + idxs[b] * EMB;
    const float lev_sms  = 1.0f / (1.0f + __expf(-e[0]));
    const float seas_sms = 1.0f / (1.0f + __expf(-e[1]));
    const float a_l = 1.0f - lev_sms;
    const float a_s = 1.0f - seas_sms;

    float buf[MM];
    const float is0 = __expf(e[2]);
    {
        float* srow = seas + b * SLEN;
        srow[0] = is0;
#pragma unroll
        for (int k = 1; k < MM; ++k) {
            float v = __expf(e[2 + k]);
            srow[k] = v;
            buf[k - 1] = v;
        }
        buf[MM - 1] = is0;
    }

    f4 pf[8];
#pragma unroll
    for (int k = 0; k < 8; ++k) {
        int flat = (k << 6) + tid;
        int r = flat >> 3, q = flat & 7;
        pf[k] = *reinterpret_cast<const f4*>(Y + (b0 + r) * TT + (q << 2));
    }

    float lev = 0.0f;

#define ES_STEP(TTI)                                                        \
    {                                                                       \
        float y  = yreg[TTI];                                               \
        float st = buf[0];                                                  \
        lev = lev_sms * __fdividef(y, st) + a_l * lev;                      \
        float ns = seas_sms * __fdividef(y, lev) + a_s * st;                \
        buf[0] = buf[1]; buf[1] = buf[2]; buf[2] = buf[3];                  \
        buf[3] = buf[4]; buf[4] = buf[5]; buf[5] = buf[6];                  \
        buf[6] = ns;                                                        \
        yl[tid][TTI] = lev;                                                 \
        se[tid][TTI] = ns;                                                  \
    }

    for (int c = 0; c < NCH; ++c) {
        __syncthreads();
#pragma unroll
        for (int k = 0; k < 8; ++k) {
            int flat = (k << 6) + tid;
            int r = flat >> 3, q = flat & 7;
            float* dst = &yl[r][q << 2];
            dst[0] = pf[k].x; dst[1] = pf[k].y; dst[2] = pf[k].z; dst[3] = pf[k].w;
        }
        __syncthreads();
        if (c < NCH - 1) {
#pragma unroll
            for (int k = 0; k < 8; ++k) {
                int flat = (k << 6) + tid;
                int r = flat >> 3, q = flat & 7;
                pf[k] = *reinterpret_cast<const f4*>(
                    Y + (b0 + r) * TT + (c + 1) * CH + (q << 2));
            }
        }

        float yreg[CH];
#pragma unroll
        for (int tt = 0; tt < CH; ++tt) yreg[tt] = yl[tid][tt];

        if (c == 0) {
            lev = __fdividef(yreg[0], is0);
            yl[tid][0] = lev;
            se[tid][0] = is0;
#pragma unroll
            for (int tt = 1; tt < CH; ++tt) ES_STEP(tt)
        } else {
#pragma unroll
            for (int tt = 0; tt < CH; ++tt) ES_STEP(tt)
        }
        __syncthreads();

#pragma unroll
        for (int k = 0; k < CH; ++k) {
            int flat = (k << 6) + tid;
            int r    = flat >> 5;
            int col  = flat & 31;
            levels[(b0 + r) * TT   + c * CH + col]      = yl[r][col];
            seas  [(b0 + r) * SLEN + MM + c * CH + col] = se[r][col];
        }
    }
#undef ES_STEP
}

// ---------------------------------------------------------------------------
// Kernel 2: streaming pass, batch-group blocked for L2 locality.
// 8 batch-groups x 128 rows; bg = blockIdx.x & 7 (round-robin XCD pin).
// Each block owns a contiguous chunk of its bg's index space (thread-stride
// 256 inside) -> small temporal working set even without XCD pinning.
// Regions within a bg (f4 units, BGB = 128):
//   A: WW*128*28  out1 f4 cols 8..35 (X c0 f4 1..13, X c1 f4 0..13, S)
//   B: WW*128*8   out1 f4 cols 0..7  (log insample 0..6, X c0 f4 0)
//   C: WW*128*7   out2 + out5
// ---------------------------------------------------------------------------
#define BGB   128
#define WBG   (WW * BGB)              // 58,496
#define NA    (WBG * 28)              // 1,637,888
#define NB    (WBG * 8)               //   467,968
#define NC    (WBG * 7)               //   409,472
#define NTOTG (NA + NB + NC)          // 2,515,328
#define BLKPG 256                     // blocks per group
#define CHUNK ((NTOTG + BLKPG - 1) / BLKPG)   // 9826

__global__ __launch_bounds__(256) void main_stream(const float* __restrict__ S,
        const float* __restrict__ Y, const float* __restrict__ X,
        const float* __restrict__ mask, const float* __restrict__ levels,
        const float* __restrict__ seas, f4* __restrict__ out1,
        f4* __restrict__ out2, f4* __restrict__ out5) {
    const int bg   = blockIdx.x & 7;
    const int blk  = blockIdx.x >> 3;
    const int bbase = bg << 7;                  // bg * 128
    const int start = blk * CHUNK;
    const int end   = min(start + CHUNK, NTOTG);

    for (int i = start + (int)threadIdx.x; i < end; i += 256) {
        if (i < NA) {
            int wb = i / 28;
            int j  = i - wb * 28;               // 0..27
            int b  = bbase + (wb & (BGB - 1));
            int w  = wb >> 7;
            f4 v;
            if (j < 13) {                       // X chan0, offsets w+4..w+55
                v = ld4u(X + (b * 2) * TT + w + ((j + 1) << 2));
            } else if (j < 27) {                // X chan1, offsets w+0..w+55
                v = ld4u(X + (b * 2 + 1) * TT + w + ((j - 13) << 2));
            } else {                            // statics
                v = *reinterpret_cast<const f4*>(S + b * NS);
            }
            __builtin_nontemporal_store(v, &out1[((w << 10) + b) * 36 + 8 + j]);
        } else if (i < NA + NB) {
            int t  = i - NA;
            int wb = t >> 3;
            int j  = t & 7;                     // 0..7
            int b  = bbase + (wb & (BGB - 1));
            int w  = wb >> 7;
            f4 v;
            if (j < 7) {                        // log insample
                int base = w + (j << 2);
                float le = levels[b * TT + w + NIN - 1];
                f4 yv = ld4u(Y    + b * TT   + base);
                f4 sv = ld4u(seas + b * SLEN + base);
                v.x = __logf(__fdividef(yv.x, le * sv.x));
                v.y = __logf(__fdividef(yv.y, le * sv.y));
                v.z = __logf(__fdividef(yv.z, le * sv.z));
                v.w = __logf(__fdividef(yv.w, le * sv.w));
            } else {                            // X chan0 offsets w+0..3
                v = ld4u(X + (b * 2) * TT + w);
            }
            __builtin_nontemporal_store(v, &out1[((w << 10) + b) * 36 + j]);
        } else {
            int t  = i - (NA + NB);
            int wb = t / 7;
            int j  = t - wb * 7;                // 0..6
            int b  = bbase + (wb & (BGB - 1));
            int w  = wb >> 7;
            int base = w + NIN + (j << 2);
            f4 vy = ld4u(Y    + b * TT + base);
            f4 vm = ld4u(mask + b * TT + base);
            int o = ((w << 10) + b) * 7 + j;
            __builtin_nontemporal_store(vy, &out2[o]);
            __builtin_nontemporal_store(vm, &out5[o]);
        }
    }
}

extern "C" void kernel_launch(void* const* d_in, const int* in_sizes, int n_in,
                              void* d_out, int out_size, void* d_ws, size_t ws_size,
                              hipStream_t stream) {
    const float* S    = (const float*)d_in[0];
    const float* Y    = (const float*)d_in[1];
    const float* X    = (const float*)d_in[2];
    const int*   idxs = (const int*)d_in[3];
    const float* mask = (const float*)d_in[4];
    const float* EW   = (const float*)d_in[5];

    float* out  = (float*)d_out;
    float* out1 = out;
    float* out2 = out1 + OUT1_SZ;
    float* out3 = out2 + OUT2_SZ;        // levels
    float* out4 = out3 + OUT3_SZ;        // seasonalities
    float* out5 = out4 + OUT4_SZ;        // mask_w

    es_scan<<<16, 64, 0, stream>>>(Y, idxs, EW, out3, out4);
    main_stream<<<8 * BLKPG, 256, 0, stream>>>(S, Y, X, mask, out3, out4,
                                               (f4*)out1, (f4*)out2, (f4*)out5);
}